// Round 16
// baseline (191.998 us; speedup 1.0000x reference)
//
#include <hip/hip_runtime.h>
#include <hip/hip_fp16.h>

#define NS 16
#define N_ATOMS 2000
#define NB 2000
#define NA 4000
#define NV 400000
#define NT 6000
#define NI 1000

#define OUT_S 819001
#define OFF_EB 0
#define OFF_EA 2000
#define OFF_EUB 6000
#define OFF_EV 6001
#define OFF_EC 406001
#define OFF_ET 806001
#define OFF_EI 812001
#define OFF_F 813001

#define CHARGE_TENTH 1.8222615f

#define NBF 44000
#define BF_BOND 0
#define BF_ANGLE 4000
#define BF_TORS 16000
#define BF_IMP 40000
#define NENTV (NV * 2)                  // 800000 vdw entries, 64B each (padded)
#define NBOND_TOT (NB + NA + NT + NI)   // 13000
#define NITEMS (NV + NB + NA + NT + NI) // 413000
#define NCB 32
#define IPB ((NITEMS + NCB - 1) / NCB)  // 12907
#define NVH (NV / 2)                    // 200000
#define VBLKH ((NVH + 255) / 256)       // 782
#define BBH ((NBOND_TOT * 2 + 255) / 256)   // 102

typedef float f2v __attribute__((ext_vector_type(2)));

__device__ __forceinline__ unsigned pkrtz(float a, float b) {
    typedef __fp16 hv2 __attribute__((ext_vector_type(2)));
    hv2 h = __builtin_amdgcn_cvt_pkrtz(a, b);
    return __builtin_bit_cast(unsigned, h);
}

// ---------------------------------------------------------------------------
// K1: fused — blocks [0,NCB): LDS histograms; blocks [NCB,..): params + E_ub.
__global__ __launch_bounds__(256, 4) void inithist_kernel(
    const float* __restrict__ v14, const float* __restrict__ q14,
    const float* __restrict__ pv, const float* __restrict__ pc,
    const int* __restrict__ nb,
    const int* __restrict__ nbi, const int* __restrict__ bidx,
    const int* __restrict__ aidx, const int* __restrict__ tidx,
    const int* __restrict__ iidx,
    float4* __restrict__ ws, int* __restrict__ countsV, int* __restrict__ countsB,
    float* __restrict__ out)
{
    __shared__ int hV[N_ATOMS];
    __shared__ int hB[N_ATOMS];
    int tid = threadIdx.x, b = blockIdx.x;

    if (b >= NCB) {
        int idx = (b - NCB) * 256 + tid;
        if (idx < NS) out[(size_t)idx * OUT_S + OFF_EUB] = 0.0f;
        if (idx < NV) {
            int v = idx;
            int i = nb[v];
            int j = nb[NV + v];
            float2 pvi = ((const float2*)pv)[i];
            float2 pvj = ((const float2*)pv)[j];
            float sigma = pvi.x + pvj.x;
            float sig2 = sigma * sigma;
            float4 w;
            w.x = sig2 * sig2 * sig2;
            w.y = pvi.y * pvj.y * 0.01f * v14[v];
            w.z = (CHARGE_TENTH * CHARGE_TENTH) * pc[i] * pc[j] * q14[v];
            w.w = 0.0f;
            ws[v] = w;
        }
        return;
    }

    for (int k = tid; k < N_ATOMS; k += 256) { hV[k] = 0; hB[k] = 0; }
    __syncthreads();
    int t0 = b * IPB, t1 = t0 + IPB; if (t1 > NITEMS) t1 = NITEMS;
    for (int t = t0 + tid; t < t1; t += 256) {
        if (t < NV) {
            atomicAdd(&hV[nbi[2 * t]], 1);
            atomicAdd(&hV[nbi[2 * t + 1]], 1);
        } else if (t < NV + NB) {
            int x = t - NV;
            atomicAdd(&hB[bidx[2 * x]], 1);
            atomicAdd(&hB[bidx[2 * x + 1]], 1);
        } else if (t < NV + NB + NA) {
            int x = t - (NV + NB);
            atomicAdd(&hB[aidx[3 * x]], 1);
            atomicAdd(&hB[aidx[3 * x + 1]], 1);
            atomicAdd(&hB[aidx[3 * x + 2]], 1);
        } else if (t < NV + NB + NA + NT) {
            int x = t - (NV + NB + NA);
            #pragma unroll
            for (int p = 0; p < 4; ++p) atomicAdd(&hB[tidx[4 * x + p]], 1);
        } else {
            int x = t - (NV + NB + NA + NT);
            #pragma unroll
            for (int p = 0; p < 4; ++p) atomicAdd(&hB[iidx[4 * x + p]], 1);
        }
    }
    __syncthreads();
    for (int k = tid; k < N_ATOMS; k += 256) {
        countsV[(size_t)b * N_ATOMS + k] = hV[k];
        countsB[(size_t)b * N_ATOMS + k] = hB[k];
    }
}

// K2: column scans.
__global__ __launch_bounds__(256) void colscan2_kernel(
    int* __restrict__ countsV, int* __restrict__ countsB,
    int* __restrict__ totalV, int* __restrict__ totalB)
{
    int a = blockIdx.x * 256 + threadIdx.x;
    if (a < N_ATOMS) {
        int pre = 0;
        for (int b = 0; b < NCB; ++b) {
            int c = countsV[(size_t)b * N_ATOMS + a];
            countsV[(size_t)b * N_ATOMS + a] = pre;
            pre += c;
        }
        totalV[a] = pre;
    } else if (a < 2 * N_ATOMS) {
        int aa = a - N_ATOMS;
        int pre = 0;
        for (int b = 0; b < NCB; ++b) {
            int c = countsB[(size_t)b * N_ATOMS + aa];
            countsB[(size_t)b * N_ATOMS + aa] = pre;
            pre += c;
        }
        totalB[aa] = pre;
    }
}

// K3: single-wave exclusive scans.
__device__ __forceinline__ void wave_scan(const int* __restrict__ total,
                                          int* __restrict__ startx, int lane)
{
    const int CH = (N_ATOMS + 63) / 64;
    int a0 = lane * CH, a1 = a0 + CH; if (a1 > N_ATOMS) a1 = N_ATOMS;
    int tot = 0;
    for (int a = a0; a < a1; ++a) tot += total[a];
    int incl = tot;
    #pragma unroll
    for (int off = 1; off < 64; off <<= 1) {
        int n = __shfl_up(incl, off);
        if (lane >= off) incl += n;
    }
    int run = incl - tot;
    for (int a = a0; a < a1; ++a) { startx[a] = run; run += total[a]; }
    if (lane == 63) startx[N_ATOMS] = run;
}

__global__ __launch_bounds__(64) void scan2_kernel(
    const int* __restrict__ totalV, const int* __restrict__ totalB,
    int* __restrict__ startxV, int* __restrict__ startxB)
{
    int lane = threadIdx.x;
    wave_scan(totalV, startxV, lane);
    wave_scan(totalB, startxB, lane);
}

// K4: placement — inverse permutations.
__global__ __launch_bounds__(256, 4) void place2_kernel(
    const int* __restrict__ nbi, const int* __restrict__ bidx,
    const int* __restrict__ aidx, const int* __restrict__ tidx,
    const int* __restrict__ iidx,
    const int* __restrict__ countsV, const int* __restrict__ countsB,
    const int* __restrict__ startxV, const int* __restrict__ startxB,
    int* __restrict__ posv, int* __restrict__ posb)
{
    __shared__ int curV[N_ATOMS];
    __shared__ int curB[N_ATOMS];
    int tid = threadIdx.x, b = blockIdx.x;
    for (int k = tid; k < N_ATOMS; k += 256) {
        curV[k] = startxV[k] + countsV[(size_t)b * N_ATOMS + k];
        curB[k] = startxB[k] + countsB[(size_t)b * N_ATOMS + k];
    }
    __syncthreads();
    int t0 = b * IPB, t1 = t0 + IPB; if (t1 > NITEMS) t1 = NITEMS;
    for (int t = t0 + tid; t < t1; t += 256) {
        if (t < NV) {
            posv[2 * t]     = atomicAdd(&curV[nbi[2 * t]], 1);
            posv[2 * t + 1] = atomicAdd(&curV[nbi[2 * t + 1]], 1);
        } else if (t < NV + NB) {
            int x = t - NV;
            #pragma unroll
            for (int sl = 0; sl < 2; ++sl)
                posb[BF_BOND + x * 2 + sl] = atomicAdd(&curB[bidx[2 * x + sl]], 1);
        } else if (t < NV + NB + NA) {
            int x = t - (NV + NB);
            #pragma unroll
            for (int sl = 0; sl < 3; ++sl)
                posb[BF_ANGLE + x * 3 + sl] = atomicAdd(&curB[aidx[3 * x + sl]], 1);
        } else if (t < NV + NB + NA + NT) {
            int x = t - (NV + NB + NA);
            #pragma unroll
            for (int sl = 0; sl < 4; ++sl)
                posb[BF_TORS + x * 4 + sl] = atomicAdd(&curB[tidx[4 * x + sl]], 1);
        } else {
            int x = t - (NV + NB + NA + NT);
            #pragma unroll
            for (int sl = 0; sl < 4; ++sl)
                posb[BF_IMP + x * 4 + sl] = atomicAdd(&curB[iidx[4 * x + sl]], 1);
        }
    }
}

// ---------------------------------------------------------------------------
// Shared phaseA compute+pack+padded-store body (entry = 64B full line).
__device__ __forceinline__ void phaseA_body(
    int v, float r[16], float2 dA[16], float2 dB[16], float2 dC[16],
    float4 w, int2 pp, unsigned* __restrict__ cV, float* __restrict__ out)
{
    unsigned cp[24];
    float hold[3][6];
    #pragma unroll
    for (int s = 0; s < 16; ++s) {
        float rinv = __builtin_amdgcn_rcpf(r[s]);
        float r2inv = rinv * rinv;
        float r6inv = r2inv * r2inv * r2inv;
        float t = w.x * r6inv;
        out[(size_t)s * OUT_S + OFF_EV + v] = w.y * (t * t - 2.0f * t);
        out[(size_t)s * OUT_S + OFF_EC + v] = w.z * rinv;
        float fsv = 12.0f * w.y * t * (1.0f - t) * rinv - w.z * r2inv;
        float cc[6];
        cc[0] = dA[s].x * fsv; cc[1] = dA[s].y * fsv; cc[2] = dB[s].x * fsv;
        cc[3] = dB[s].y * fsv; cc[4] = dC[s].x * fsv; cc[5] = dC[s].y * fsv;
        int m = s & 3;
        if (m < 3) {
            #pragma unroll
            for (int k = 0; k < 6; ++k) hold[m][k] = cc[k];
        } else {
            int q = s >> 2;
            #pragma unroll
            for (int k = 0; k < 6; ++k) {
                int t0 = __builtin_amdgcn_cvt_pk_fp8_f32(hold[0][k], hold[1][k], 0, false);
                t0 = __builtin_amdgcn_cvt_pk_fp8_f32(hold[2][k], cc[k], t0, true);
                cp[(k / 3) * 12 + (k % 3) * 4 + q] = (unsigned)t0;
            }
        }
    }
    uint4 zero = make_uint4(0u, 0u, 0u, 0u);
    uint4* dst0 = (uint4*)(cV + (size_t)pp.x * 16);
    #pragma unroll
    for (int k = 0; k < 3; ++k)
        dst0[k] = make_uint4(cp[4 * k], cp[4 * k + 1], cp[4 * k + 2], cp[4 * k + 3]);
    dst0[3] = zero;
    uint4* dst1 = (uint4*)(cV + (size_t)pp.y * 16);
    #pragma unroll
    for (int k = 0; k < 3; ++k)
        dst1[k] = make_uint4(cp[12 + 4 * k], cp[12 + 4 * k + 1], cp[12 + 4 * k + 2], cp[12 + 4 * k + 3]);
    dst1[3] = zero;
}

// K5a: phaseA half 0 — DIRECT 24B-stride loads, padded 64B stores.
__global__ __launch_bounds__(256, 4) void workA_kernel(
    const float* __restrict__ lv, const float* __restrict__ dlv,
    const float4* __restrict__ ws, const int* __restrict__ posv,
    unsigned* __restrict__ cV, float* __restrict__ out)
{
    int v = blockIdx.x * 256 + threadIdx.x;
    if (v >= NVH) return;
    float4 w = ws[v];
    int2 pp = *(const int2*)(posv + 2 * v);
    float r[16]; float2 dA[16], dB[16], dC[16];
    #pragma unroll
    for (int s = 0; s < 16; ++s) {
        const float2* d2 = (const float2*)(dlv + ((size_t)s * NV + v) * 6);
        dA[s] = d2[0]; dB[s] = d2[1]; dC[s] = d2[2];
        r[s] = lv[(size_t)s * NV + v];
    }
    phaseA_body(v, r, dA, dB, dC, w, pp, cV, out);
}

// K5b: bonded (blocks [0,BBH)) + phaseA half 1 with LDS-STAGED coalesced loads.
__global__ __launch_bounds__(256, 4) void workB_kernel(
    const float* __restrict__ lv, const float* __restrict__ dlv,
    const float4* __restrict__ ws, const int* __restrict__ posv,
    const float* __restrict__ lb, const float* __restrict__ th,
    const float* __restrict__ sc, const float* __restrict__ c2i,
    const float* __restrict__ pb, const float* __restrict__ pa,
    const float* __restrict__ pt, const float* __restrict__ pim,
    const float* __restrict__ dlb, const float* __restrict__ dth,
    const float* __restrict__ dtt, const float* __restrict__ dc2,
    const int* __restrict__ posb,
    unsigned* __restrict__ cV, unsigned* __restrict__ cB,
    float* __restrict__ out)
{
    __shared__ float4 stage[4][96];
    int x = blockIdx.x;
    int tid = threadIdx.x;

    if (x >= BBH) {
        int wv = tid >> 6, lane = tid & 63;
        int vbase = NVH + (x - BBH) * 256 + wv * 64;
        if (vbase >= NV) return;
        int v = vbase + lane;
        float4 w = ws[v];
        int2 pp = *(const int2*)(posv + 2 * v);
        float4* st = stage[wv];
        const float4* dfl4 = (const float4*)dlv;
        float r[16]; float2 dA[16], dB[16], dC[16];
        #pragma unroll
        for (int s = 0; s < 16; ++s) {
            size_t f4base = ((size_t)s * NV + vbase) / 2 * 3;
            float4 t0 = dfl4[f4base + lane];
            float4 t1;
            if (lane < 32) t1 = dfl4[f4base + 64 + lane];
            st[lane] = t0;
            if (lane < 32) st[64 + lane] = t1;
            asm volatile("s_waitcnt lgkmcnt(0)" ::: "memory");
            const float2* stp = (const float2*)st;
            dA[s] = stp[lane * 3];
            dB[s] = stp[lane * 3 + 1];
            dC[s] = stp[lane * 3 + 2];
            r[s] = lv[(size_t)s * NV + v];
        }
        phaseA_body(v, r, dA, dB, dC, w, pp, cV, out);
        return;
    }

    // ---------------- bonded, h-split (cB layout unchanged) ----------------
    int idx = x * 256 + tid;
    int h = idx & 1;
    int t = idx >> 1;
    if (t >= NBOND_TOT) return;
    int sbase = h * 8;

    if (t < NB) {
        int b = t;
        float2 p = ((const float2*)pb)[b];
        float K = p.x * 100.0f;
        unsigned cp[24]; float hold[6];
        #pragma unroll
        for (int j = 0; j < 8; ++j) {
            int s = sbase + j;
            float d = lb[s * NB + b] - p.y;
            out[(size_t)s * OUT_S + OFF_EB + b] = K * d * d;
            float g = 2.0f * K * d;
            const float2* dd = (const float2*)(dlb + ((size_t)s * NB + b) * 6);
            float2 dA = dd[0], dB = dd[1], dC = dd[2];
            float v0 = dA.x * g, v1 = dA.y * g, v2 = dB.x * g;
            float v3 = dB.y * g, v4 = dC.x * g, v5 = dC.y * g;
            if ((j & 1) == 0) { hold[0]=v0; hold[1]=v1; hold[2]=v2; hold[3]=v3; hold[4]=v4; hold[5]=v5; }
            else {
                int q = j >> 1;
                cp[0*12 + 0*4 + q] = pkrtz(hold[0], v0);
                cp[0*12 + 1*4 + q] = pkrtz(hold[1], v1);
                cp[0*12 + 2*4 + q] = pkrtz(hold[2], v2);
                cp[1*12 + 0*4 + q] = pkrtz(hold[3], v3);
                cp[1*12 + 1*4 + q] = pkrtz(hold[4], v4);
                cp[1*12 + 2*4 + q] = pkrtz(hold[5], v5);
            }
        }
        #pragma unroll
        for (int sl = 0; sl < 2; ++sl) {
            uint4* dst = (uint4*)(cB + (size_t)posb[BF_BOND + b * 2 + sl] * 24 + h * 12);
            #pragma unroll
            for (int k = 0; k < 3; ++k)
                dst[k] = make_uint4(cp[sl*12+4*k], cp[sl*12+4*k+1], cp[sl*12+4*k+2], cp[sl*12+4*k+3]);
        }
    } else if (t < NB + NA) {
        int a = t - NB;
        float2 p = ((const float2*)pa)[a];
        float Ka = p.x * 10.0f;
        float th0 = p.y * 0.31415926535f;
        unsigned cp[36]; float hold[9];
        #pragma unroll
        for (int j = 0; j < 8; ++j) {
            int s = sbase + j;
            float da = th[s * NA + a] - th0;
            out[(size_t)s * OUT_S + OFF_EA + a] = Ka * da * da;
            float g = 2.0f * Ka * da;
            const float* dd = dth + ((size_t)s * NA + a) * 9;
            float v[9];
            #pragma unroll
            for (int k = 0; k < 9; ++k) v[k] = dd[k] * g;
            if ((j & 1) == 0) {
                #pragma unroll
                for (int k = 0; k < 9; ++k) hold[k] = v[k];
            } else {
                int q = j >> 1;
                #pragma unroll
                for (int k = 0; k < 9; ++k)
                    cp[(k / 3) * 12 + (k % 3) * 4 + q] = pkrtz(hold[k], v[k]);
            }
        }
        #pragma unroll
        for (int sl = 0; sl < 3; ++sl) {
            uint4* dst = (uint4*)(cB + (size_t)posb[BF_ANGLE + a * 3 + sl] * 24 + h * 12);
            #pragma unroll
            for (int k = 0; k < 3; ++k)
                dst[k] = make_uint4(cp[sl*12+4*k], cp[sl*12+4*k+1], cp[sl*12+4*k+2], cp[sl*12+4*k+3]);
        }
    } else if (t < NB + NA + NT) {
        int tt = t - (NB + NA);
        float4 p4 = ((const float4*)pt)[tt];
        unsigned cp[48]; float hold[12];
        #pragma unroll
        for (int j = 0; j < 8; ++j) {
            int s = sbase + j;
            const float4* s8 = (const float4*)(sc + ((size_t)s * NT + tt) * 8);
            float4 sA = s8[0], sB = s8[1];
            out[(size_t)s * OUT_S + OFF_ET + tt] =
                sA.y * p4.x + sA.w * p4.y + sB.y * p4.z + sB.w * p4.w;
            float g = -(sA.x * p4.x + sA.z * p4.y * 2.0f + sB.x * p4.z * 3.0f + sB.z * p4.w * 4.0f);
            const float4* dd = (const float4*)(dtt + ((size_t)s * NT + tt) * 12);
            float4 dA = dd[0], dB = dd[1], dC = dd[2];
            float v[12] = {dA.x*g, dA.y*g, dA.z*g, dA.w*g, dB.x*g, dB.y*g,
                           dB.z*g, dB.w*g, dC.x*g, dC.y*g, dC.z*g, dC.w*g};
            if ((j & 1) == 0) {
                #pragma unroll
                for (int k = 0; k < 12; ++k) hold[k] = v[k];
            } else {
                int q = j >> 1;
                #pragma unroll
                for (int k = 0; k < 12; ++k)
                    cp[(k / 3) * 12 + (k % 3) * 4 + q] = pkrtz(hold[k], v[k]);
            }
        }
        #pragma unroll
        for (int sl = 0; sl < 4; ++sl) {
            uint4* dst = (uint4*)(cB + (size_t)posb[BF_TORS + tt * 4 + sl] * 24 + h * 12);
            #pragma unroll
            for (int k = 0; k < 3; ++k)
                dst[k] = make_uint4(cp[sl*12+4*k], cp[sl*12+4*k+1], cp[sl*12+4*k+2], cp[sl*12+4*k+3]);
        }
    } else {
        int ii = t - (NB + NA + NT);
        float ki = pim[ii];
        float g = -ki;
        unsigned cp[48]; float hold[12];
        #pragma unroll
        for (int j = 0; j < 8; ++j) {
            int s = sbase + j;
            out[(size_t)s * OUT_S + OFF_EI + ii] = ki * (1.0f - c2i[s * NI + ii]);
            const float4* dd = (const float4*)(dc2 + ((size_t)s * NI + ii) * 12);
            float4 dA = dd[0], dB = dd[1], dC = dd[2];
            float v[12] = {dA.x*g, dA.y*g, dA.z*g, dA.w*g, dB.x*g, dB.y*g,
                           dB.z*g, dB.w*g, dC.x*g, dC.y*g, dC.z*g, dC.w*g};
            if ((j & 1) == 0) {
                #pragma unroll
                for (int k = 0; k < 12; ++k) hold[k] = v[k];
            } else {
                int q = j >> 1;
                #pragma unroll
                for (int k = 0; k < 12; ++k)
                    cp[(k / 3) * 12 + (k % 3) * 4 + q] = pkrtz(hold[k], v[k]);
            }
        }
        #pragma unroll
        for (int sl = 0; sl < 4; ++sl) {
            uint4* dst = (uint4*)(cB + (size_t)posb[BF_IMP + ii * 4 + sl] * 24 + h * 12);
            #pragma unroll
            for (int k = 0; k < 3; ++k)
                dst[k] = make_uint4(cp[sl*12+4*k], cp[sl*12+4*k+1], cp[sl*12+4*k+2], cp[sl*12+4*k+3]);
        }
    }
}

// ---------------------------------------------------------------------------
// K6: gather — cV stride now 16 words (64B entries, first 12 words used).
__global__ __launch_bounds__(256, 2) void gather2_kernel(
    const unsigned* __restrict__ cV, const unsigned* __restrict__ cB,
    const int* __restrict__ startxV, const int* __restrict__ startxB,
    float* __restrict__ out)
{
    __shared__ float red[4][48];
    int wv = threadIdx.x >> 6, lane = threadIdx.x & 63;
    int a0 = blockIdx.x * 4;
    int a = a0 + wv;

    float acc[48];
    #pragma unroll
    for (int k = 0; k < 48; ++k) acc[k] = 0.0f;

    {
        int base = startxV[a], endp = startxV[a + 1];
        for (int i = base + lane; i < endp; i += 64) {
            const uint4* e = (const uint4*)(cV + (size_t)i * 16);
            uint4 q0 = e[0], q1 = e[1], q2 = e[2];
            unsigned wd[12] = {q0.x, q0.y, q0.z, q0.w,
                               q1.x, q1.y, q1.z, q1.w,
                               q2.x, q2.y, q2.z, q2.w};
            #pragma unroll
            for (int wi = 0; wi < 12; ++wi) {
                int comp = wi >> 2, q = wi & 3;
                f2v lo = __builtin_amdgcn_cvt_pk_f32_fp8(wd[wi], false);
                f2v hi = __builtin_amdgcn_cvt_pk_f32_fp8(wd[wi], true);
                acc[comp * 16 + 4 * q + 0] += lo.x;
                acc[comp * 16 + 4 * q + 1] += lo.y;
                acc[comp * 16 + 4 * q + 2] += hi.x;
                acc[comp * 16 + 4 * q + 3] += hi.y;
            }
        }
    }
    {
        int base = startxB[a], endp = startxB[a + 1];
        for (int i = base + lane; i < endp; i += 64) {
            const uint4* e = (const uint4*)(cB + (size_t)i * 24);
            uint4 q0 = e[0], q1 = e[1], q2 = e[2], q3 = e[3], q4 = e[4], q5 = e[5];
            unsigned wd[24] = {q0.x, q0.y, q0.z, q0.w, q1.x, q1.y, q1.z, q1.w,
                               q2.x, q2.y, q2.z, q2.w, q3.x, q3.y, q3.z, q3.w,
                               q4.x, q4.y, q4.z, q4.w, q5.x, q5.y, q5.z, q5.w};
            #pragma unroll
            for (int wi = 0; wi < 24; ++wi) {
                int h = wi / 12, rem = wi - h * 12;
                int comp = rem >> 2, qq = rem & 3;
                int s0 = h * 8 + 2 * qq;
                __half2 hh = __builtin_bit_cast(__half2, wd[wi]);
                acc[comp * 16 + s0]     += __low2float(hh);
                acc[comp * 16 + s0 + 1] += __high2float(hh);
            }
        }
    }

    #pragma unroll
    for (int off = 32; off > 0; off >>= 1) {
        #pragma unroll
        for (int k = 0; k < 48; ++k)
            acc[k] += __shfl_down(acc[k], off);
    }
    if (lane == 0) {
        #pragma unroll
        for (int k = 0; k < 48; ++k) red[wv][k] = acc[k];
    }
    __syncthreads();
    int th = threadIdx.x;
    if (th < 192) {
        int s = th / 12, idx = th % 12;
        int ai = idx / 3, comp = idx % 3;
        out[(size_t)s * OUT_S + OFF_F + 3 * (a0 + ai) + comp] = red[ai][comp * 16 + s];
    }
}

// ---------------------------------------------------------------------------
extern "C" void kernel_launch(void* const* d_in, const int* in_sizes, int n_in,
                              void* d_out, int out_size, void* d_ws, size_t ws_size,
                              hipStream_t stream) {
    const float* lb  = (const float*)d_in[0];
    const float* th  = (const float*)d_in[1];
    const float* lv  = (const float*)d_in[2];
    const float* sc  = (const float*)d_in[3];
    const float* c2i = (const float*)d_in[4];
    const float* v14 = (const float*)d_in[5];
    const float* q14 = (const float*)d_in[6];
    const float* pb  = (const float*)d_in[7];
    const float* pa  = (const float*)d_in[8];
    const float* pv  = (const float*)d_in[9];
    const float* pc  = (const float*)d_in[10];
    const float* pt  = (const float*)d_in[11];
    const float* pim = (const float*)d_in[12];
    const float* dlb = (const float*)d_in[13];
    const float* dth = (const float*)d_in[14];
    const float* dlv = (const float*)d_in[15];
    const float* dtt = (const float*)d_in[16];
    const float* dc2 = (const float*)d_in[17];
    const int* nb    = (const int*)d_in[18];
    const int* bidx  = (const int*)d_in[19];
    const int* aidx  = (const int*)d_in[20];
    const int* nbi   = (const int*)d_in[21];
    const int* tidx  = (const int*)d_in[22];
    const int* iidx  = (const int*)d_in[23];
    float* out = (float*)d_out;

    unsigned* cV      = (unsigned*)d_ws;                    // NENTV*16 u32 = 51.2MB
    unsigned* cB      = cV + (size_t)NENTV * 16;            // NBF*24 u32
    float4*   wsp     = (float4*)(cB + (size_t)NBF * 24);   // NV
    int*      posv    = (int*)(wsp + NV);                   // 2*NV
    int*      posb    = posv + 2 * NV;                      // NBF
    int*      countsV = posb + NBF;                         // NCB*N_ATOMS
    int*      countsB = countsV + (size_t)NCB * N_ATOMS;    // NCB*N_ATOMS
    int*      totalV  = countsB + (size_t)NCB * N_ATOMS;    // N_ATOMS
    int*      totalB  = totalV + N_ATOMS;                   // N_ATOMS
    int*      startxV = totalB + N_ATOMS;                   // N_ATOMS+1
    int*      startxB = startxV + (N_ATOMS + 1);            // N_ATOMS+1

    inithist_kernel<<<NCB + (NV + 255) / 256, 256, 0, stream>>>(
        v14, q14, pv, pc, nb, nbi, bidx, aidx, tidx, iidx,
        wsp, countsV, countsB, out);
    colscan2_kernel<<<(2 * N_ATOMS + 255) / 256, 256, 0, stream>>>(countsV, countsB, totalV, totalB);
    scan2_kernel<<<1, 64, 0, stream>>>(totalV, totalB, startxV, startxB);
    place2_kernel<<<NCB, 256, 0, stream>>>(nbi, bidx, aidx, tidx, iidx,
                                           countsV, countsB, startxV, startxB, posv, posb);
    workA_kernel<<<VBLKH, 256, 0, stream>>>(lv, dlv, wsp, posv, cV, out);
    workB_kernel<<<BBH + VBLKH, 256, 0, stream>>>(
        lv, dlv, wsp, posv, lb, th, sc, c2i, pb, pa, pt, pim,
        dlb, dth, dtt, dc2, posb, cV, cB, out);
    gather2_kernel<<<N_ATOMS / 4, 256, 0, stream>>>(cV, cB, startxV, startxB, out);
}

// Round 17
// 134.083 us; speedup vs baseline: 1.4319x; 1.4319x over previous
//
#include <hip/hip_runtime.h>
#include <hip/hip_fp16.h>

#define NS 16
#define N_ATOMS 2000
#define NB 2000
#define NA 4000
#define NV 400000
#define NT 6000
#define NI 1000

#define OUT_S 819001
#define OFF_EB 0
#define OFF_EA 2000
#define OFF_EUB 6000
#define OFF_EV 6001
#define OFF_EC 406001
#define OFF_ET 806001
#define OFF_EI 812001
#define OFF_F 813001

#define CHARGE_TENTH 1.8222615f

#define NBF 44000
#define BF_BOND 0
#define BF_ANGLE 4000
#define BF_TORS 16000
#define BF_IMP 40000
#define NENTV (NV * 2)
#define NBOND_TOT (NB + NA + NT + NI)   // 13000
#define NITEMS (NV + NB + NA + NT + NI) // 413000
#define NCB 64
#define IPB ((NITEMS + NCB - 1) / NCB)  // 6454
#define VBLKS ((NV + 255) / 256)        // 1563
#define BBH ((NBOND_TOT * 2 + 255) / 256)   // 102

typedef float f2v __attribute__((ext_vector_type(2)));

__device__ __forceinline__ unsigned pkrtz(float a, float b) {
    typedef __fp16 hv2 __attribute__((ext_vector_type(2)));
    hv2 h = __builtin_amdgcn_cvt_pkrtz(a, b);
    return __builtin_bit_cast(unsigned, h);
}

// ---------------------------------------------------------------------------
// K1: fused — blocks [0,NCB): LDS histograms; blocks [NCB,..): params + E_ub.
__global__ __launch_bounds__(256, 4) void inithist_kernel(
    const float* __restrict__ v14, const float* __restrict__ q14,
    const float* __restrict__ pv, const float* __restrict__ pc,
    const int* __restrict__ nb,
    const int* __restrict__ nbi, const int* __restrict__ bidx,
    const int* __restrict__ aidx, const int* __restrict__ tidx,
    const int* __restrict__ iidx,
    float4* __restrict__ ws, int* __restrict__ countsV, int* __restrict__ countsB,
    float* __restrict__ out)
{
    __shared__ int hV[N_ATOMS];
    __shared__ int hB[N_ATOMS];
    int tid = threadIdx.x, b = blockIdx.x;

    if (b >= NCB) {
        int idx = (b - NCB) * 256 + tid;
        if (idx < NS) out[(size_t)idx * OUT_S + OFF_EUB] = 0.0f;
        if (idx < NV) {
            int v = idx;
            int i = nb[v];
            int j = nb[NV + v];
            float2 pvi = ((const float2*)pv)[i];
            float2 pvj = ((const float2*)pv)[j];
            float sigma = pvi.x + pvj.x;
            float sig2 = sigma * sigma;
            float4 w;
            w.x = sig2 * sig2 * sig2;
            w.y = pvi.y * pvj.y * 0.01f * v14[v];
            w.z = (CHARGE_TENTH * CHARGE_TENTH) * pc[i] * pc[j] * q14[v];
            w.w = 0.0f;
            ws[v] = w;
        }
        return;
    }

    for (int k = tid; k < N_ATOMS; k += 256) { hV[k] = 0; hB[k] = 0; }
    __syncthreads();
    int t0 = b * IPB, t1 = t0 + IPB; if (t1 > NITEMS) t1 = NITEMS;
    for (int t = t0 + tid; t < t1; t += 256) {
        if (t < NV) {
            atomicAdd(&hV[nbi[2 * t]], 1);
            atomicAdd(&hV[nbi[2 * t + 1]], 1);
        } else if (t < NV + NB) {
            int x = t - NV;
            atomicAdd(&hB[bidx[2 * x]], 1);
            atomicAdd(&hB[bidx[2 * x + 1]], 1);
        } else if (t < NV + NB + NA) {
            int x = t - (NV + NB);
            atomicAdd(&hB[aidx[3 * x]], 1);
            atomicAdd(&hB[aidx[3 * x + 1]], 1);
            atomicAdd(&hB[aidx[3 * x + 2]], 1);
        } else if (t < NV + NB + NA + NT) {
            int x = t - (NV + NB + NA);
            #pragma unroll
            for (int p = 0; p < 4; ++p) atomicAdd(&hB[tidx[4 * x + p]], 1);
        } else {
            int x = t - (NV + NB + NA + NT);
            #pragma unroll
            for (int p = 0; p < 4; ++p) atomicAdd(&hB[iidx[4 * x + p]], 1);
        }
    }
    __syncthreads();
    for (int k = tid; k < N_ATOMS; k += 256) {
        countsV[(size_t)b * N_ATOMS + k] = hV[k];
        countsB[(size_t)b * N_ATOMS + k] = hB[k];
    }
}

// K2: column scans.
__global__ __launch_bounds__(256) void colscan2_kernel(
    int* __restrict__ countsV, int* __restrict__ countsB,
    int* __restrict__ totalV, int* __restrict__ totalB)
{
    int a = blockIdx.x * 256 + threadIdx.x;
    if (a < N_ATOMS) {
        int pre = 0;
        for (int b = 0; b < NCB; ++b) {
            int c = countsV[(size_t)b * N_ATOMS + a];
            countsV[(size_t)b * N_ATOMS + a] = pre;
            pre += c;
        }
        totalV[a] = pre;
    } else if (a < 2 * N_ATOMS) {
        int aa = a - N_ATOMS;
        int pre = 0;
        for (int b = 0; b < NCB; ++b) {
            int c = countsB[(size_t)b * N_ATOMS + aa];
            countsB[(size_t)b * N_ATOMS + aa] = pre;
            pre += c;
        }
        totalB[aa] = pre;
    }
}

// K3: single-wave exclusive scans.
__device__ __forceinline__ void wave_scan(const int* __restrict__ total,
                                          int* __restrict__ startx, int lane)
{
    const int CH = (N_ATOMS + 63) / 64;
    int a0 = lane * CH, a1 = a0 + CH; if (a1 > N_ATOMS) a1 = N_ATOMS;
    int tot = 0;
    for (int a = a0; a < a1; ++a) tot += total[a];
    int incl = tot;
    #pragma unroll
    for (int off = 1; off < 64; off <<= 1) {
        int n = __shfl_up(incl, off);
        if (lane >= off) incl += n;
    }
    int run = incl - tot;
    for (int a = a0; a < a1; ++a) { startx[a] = run; run += total[a]; }
    if (lane == 63) startx[N_ATOMS] = run;
}

__global__ __launch_bounds__(64) void scan2_kernel(
    const int* __restrict__ totalV, const int* __restrict__ totalB,
    int* __restrict__ startxV, int* __restrict__ startxB)
{
    int lane = threadIdx.x;
    wave_scan(totalV, startxV, lane);
    wave_scan(totalB, startxB, lane);
}

// K4: placement — inverse permutations.
__global__ __launch_bounds__(256, 4) void place2_kernel(
    const int* __restrict__ nbi, const int* __restrict__ bidx,
    const int* __restrict__ aidx, const int* __restrict__ tidx,
    const int* __restrict__ iidx,
    const int* __restrict__ countsV, const int* __restrict__ countsB,
    const int* __restrict__ startxV, const int* __restrict__ startxB,
    int* __restrict__ posv, int* __restrict__ posb)
{
    __shared__ int curV[N_ATOMS];
    __shared__ int curB[N_ATOMS];
    int tid = threadIdx.x, b = blockIdx.x;
    for (int k = tid; k < N_ATOMS; k += 256) {
        curV[k] = startxV[k] + countsV[(size_t)b * N_ATOMS + k];
        curB[k] = startxB[k] + countsB[(size_t)b * N_ATOMS + k];
    }
    __syncthreads();
    int t0 = b * IPB, t1 = t0 + IPB; if (t1 > NITEMS) t1 = NITEMS;
    for (int t = t0 + tid; t < t1; t += 256) {
        if (t < NV) {
            posv[2 * t]     = atomicAdd(&curV[nbi[2 * t]], 1);
            posv[2 * t + 1] = atomicAdd(&curV[nbi[2 * t + 1]], 1);
        } else if (t < NV + NB) {
            int x = t - NV;
            #pragma unroll
            for (int sl = 0; sl < 2; ++sl)
                posb[BF_BOND + x * 2 + sl] = atomicAdd(&curB[bidx[2 * x + sl]], 1);
        } else if (t < NV + NB + NA) {
            int x = t - (NV + NB);
            #pragma unroll
            for (int sl = 0; sl < 3; ++sl)
                posb[BF_ANGLE + x * 3 + sl] = atomicAdd(&curB[aidx[3 * x + sl]], 1);
        } else if (t < NV + NB + NA + NT) {
            int x = t - (NV + NB + NA);
            #pragma unroll
            for (int sl = 0; sl < 4; ++sl)
                posb[BF_TORS + x * 4 + sl] = atomicAdd(&curB[tidx[4 * x + sl]], 1);
        } else {
            int x = t - (NV + NB + NA + NT);
            #pragma unroll
            for (int sl = 0; sl < 4; ++sl)
                posb[BF_IMP + x * 4 + sl] = atomicAdd(&curB[iidx[4 * x + sl]], 1);
        }
    }
}

// ---------------------------------------------------------------------------
// K5: fused work. Blocks [0,BBH): bonded h-split; blocks [BBH,..): phaseA
// per-v, 16 samples, fp8 48B entries. E values buffered in registers and
// written AFTER the loop (no stores between load rounds).
__global__ __launch_bounds__(256, 4) void work_kernel(
    const float* __restrict__ lv, const float* __restrict__ dlv,
    const float4* __restrict__ ws, const int* __restrict__ posv,
    const float* __restrict__ lb, const float* __restrict__ th,
    const float* __restrict__ sc, const float* __restrict__ c2i,
    const float* __restrict__ pb, const float* __restrict__ pa,
    const float* __restrict__ pt, const float* __restrict__ pim,
    const float* __restrict__ dlb, const float* __restrict__ dth,
    const float* __restrict__ dtt, const float* __restrict__ dc2,
    const int* __restrict__ posb,
    unsigned* __restrict__ cV, unsigned* __restrict__ cB,
    float* __restrict__ out)
{
    int x = blockIdx.x;
    int tid = threadIdx.x;

    if (x >= BBH) {
        // ---------------- phaseA ----------------
        int v = (x - BBH) * 256 + tid;
        if (v >= NV) return;
        float4 w = ws[v];
        int2 pp = *(const int2*)(posv + 2 * v);
        unsigned cp[24];
        float hold[3][6];
        float ev[16], ec[16];
        #pragma unroll
        for (int s = 0; s < 16; ++s) {
            float r = lv[(size_t)s * NV + v];
            const float2* d2 = (const float2*)(dlv + ((size_t)s * NV + v) * 6);
            float2 dA = d2[0], dB = d2[1], dC = d2[2];
            float rinv = __builtin_amdgcn_rcpf(r);
            float r2inv = rinv * rinv;
            float r6inv = r2inv * r2inv * r2inv;
            float t = w.x * r6inv;
            ev[s] = w.y * (t * t - 2.0f * t);
            ec[s] = w.z * rinv;
            float fsv = 12.0f * w.y * t * (1.0f - t) * rinv - w.z * r2inv;
            float cc[6];
            cc[0] = dA.x * fsv; cc[1] = dA.y * fsv; cc[2] = dB.x * fsv;
            cc[3] = dB.y * fsv; cc[4] = dC.x * fsv; cc[5] = dC.y * fsv;
            int m = s & 3;
            if (m < 3) {
                #pragma unroll
                for (int k = 0; k < 6; ++k) hold[m][k] = cc[k];
            } else {
                int q = s >> 2;
                #pragma unroll
                for (int k = 0; k < 6; ++k) {
                    int t0 = __builtin_amdgcn_cvt_pk_fp8_f32(hold[0][k], hold[1][k], 0, false);
                    t0 = __builtin_amdgcn_cvt_pk_fp8_f32(hold[2][k], cc[k], t0, true);
                    cp[(k / 3) * 12 + (k % 3) * 4 + q] = (unsigned)t0;
                }
            }
        }
        uint4* dst0 = (uint4*)(cV + (size_t)pp.x * 12);
        #pragma unroll
        for (int k = 0; k < 3; ++k)
            dst0[k] = make_uint4(cp[4 * k], cp[4 * k + 1], cp[4 * k + 2], cp[4 * k + 3]);
        uint4* dst1 = (uint4*)(cV + (size_t)pp.y * 12);
        #pragma unroll
        for (int k = 0; k < 3; ++k)
            dst1[k] = make_uint4(cp[12 + 4 * k], cp[12 + 4 * k + 1], cp[12 + 4 * k + 2], cp[12 + 4 * k + 3]);
        #pragma unroll
        for (int s = 0; s < 16; ++s) {
            out[(size_t)s * OUT_S + OFF_EV + v] = ev[s];
            out[(size_t)s * OUT_S + OFF_EC + v] = ec[s];
        }
        return;
    }

    // ---------------- bonded, h-split ----------------
    int idx = x * 256 + tid;
    int h = idx & 1;           // sample-half
    int t = idx >> 1;          // term id
    if (t >= NBOND_TOT) return;
    int sbase = h * 8;

    if (t < NB) {
        int b = t;
        float2 p = ((const float2*)pb)[b];
        float K = p.x * 100.0f;
        unsigned cp[24]; float hold[6];
        #pragma unroll
        for (int j = 0; j < 8; ++j) {
            int s = sbase + j;
            float d = lb[s * NB + b] - p.y;
            out[(size_t)s * OUT_S + OFF_EB + b] = K * d * d;
            float g = 2.0f * K * d;
            const float2* dd = (const float2*)(dlb + ((size_t)s * NB + b) * 6);
            float2 dA = dd[0], dB = dd[1], dC = dd[2];
            float v0 = dA.x * g, v1 = dA.y * g, v2 = dB.x * g;
            float v3 = dB.y * g, v4 = dC.x * g, v5 = dC.y * g;
            if ((j & 1) == 0) { hold[0]=v0; hold[1]=v1; hold[2]=v2; hold[3]=v3; hold[4]=v4; hold[5]=v5; }
            else {
                int q = j >> 1;
                cp[0*12 + 0*4 + q] = pkrtz(hold[0], v0);
                cp[0*12 + 1*4 + q] = pkrtz(hold[1], v1);
                cp[0*12 + 2*4 + q] = pkrtz(hold[2], v2);
                cp[1*12 + 0*4 + q] = pkrtz(hold[3], v3);
                cp[1*12 + 1*4 + q] = pkrtz(hold[4], v4);
                cp[1*12 + 2*4 + q] = pkrtz(hold[5], v5);
            }
        }
        #pragma unroll
        for (int sl = 0; sl < 2; ++sl) {
            uint4* dst = (uint4*)(cB + (size_t)posb[BF_BOND + b * 2 + sl] * 24 + h * 12);
            #pragma unroll
            for (int k = 0; k < 3; ++k)
                dst[k] = make_uint4(cp[sl*12+4*k], cp[sl*12+4*k+1], cp[sl*12+4*k+2], cp[sl*12+4*k+3]);
        }
    } else if (t < NB + NA) {
        int a = t - NB;
        float2 p = ((const float2*)pa)[a];
        float Ka = p.x * 10.0f;
        float th0 = p.y * 0.31415926535f;
        unsigned cp[36]; float hold[9];
        #pragma unroll
        for (int j = 0; j < 8; ++j) {
            int s = sbase + j;
            float da = th[s * NA + a] - th0;
            out[(size_t)s * OUT_S + OFF_EA + a] = Ka * da * da;
            float g = 2.0f * Ka * da;
            const float* dd = dth + ((size_t)s * NA + a) * 9;
            float v[9];
            #pragma unroll
            for (int k = 0; k < 9; ++k) v[k] = dd[k] * g;
            if ((j & 1) == 0) {
                #pragma unroll
                for (int k = 0; k < 9; ++k) hold[k] = v[k];
            } else {
                int q = j >> 1;
                #pragma unroll
                for (int k = 0; k < 9; ++k)
                    cp[(k / 3) * 12 + (k % 3) * 4 + q] = pkrtz(hold[k], v[k]);
            }
        }
        #pragma unroll
        for (int sl = 0; sl < 3; ++sl) {
            uint4* dst = (uint4*)(cB + (size_t)posb[BF_ANGLE + a * 3 + sl] * 24 + h * 12);
            #pragma unroll
            for (int k = 0; k < 3; ++k)
                dst[k] = make_uint4(cp[sl*12+4*k], cp[sl*12+4*k+1], cp[sl*12+4*k+2], cp[sl*12+4*k+3]);
        }
    } else if (t < NB + NA + NT) {
        int tt = t - (NB + NA);
        float4 p4 = ((const float4*)pt)[tt];
        unsigned cp[48]; float hold[12];
        #pragma unroll
        for (int j = 0; j < 8; ++j) {
            int s = sbase + j;
            const float4* s8 = (const float4*)(sc + ((size_t)s * NT + tt) * 8);
            float4 sA = s8[0], sB = s8[1];
            out[(size_t)s * OUT_S + OFF_ET + tt] =
                sA.y * p4.x + sA.w * p4.y + sB.y * p4.z + sB.w * p4.w;
            float g = -(sA.x * p4.x + sA.z * p4.y * 2.0f + sB.x * p4.z * 3.0f + sB.z * p4.w * 4.0f);
            const float4* dd = (const float4*)(dtt + ((size_t)s * NT + tt) * 12);
            float4 dA = dd[0], dB = dd[1], dC = dd[2];
            float v[12] = {dA.x*g, dA.y*g, dA.z*g, dA.w*g, dB.x*g, dB.y*g,
                           dB.z*g, dB.w*g, dC.x*g, dC.y*g, dC.z*g, dC.w*g};
            if ((j & 1) == 0) {
                #pragma unroll
                for (int k = 0; k < 12; ++k) hold[k] = v[k];
            } else {
                int q = j >> 1;
                #pragma unroll
                for (int k = 0; k < 12; ++k)
                    cp[(k / 3) * 12 + (k % 3) * 4 + q] = pkrtz(hold[k], v[k]);
            }
        }
        #pragma unroll
        for (int sl = 0; sl < 4; ++sl) {
            uint4* dst = (uint4*)(cB + (size_t)posb[BF_TORS + tt * 4 + sl] * 24 + h * 12);
            #pragma unroll
            for (int k = 0; k < 3; ++k)
                dst[k] = make_uint4(cp[sl*12+4*k], cp[sl*12+4*k+1], cp[sl*12+4*k+2], cp[sl*12+4*k+3]);
        }
    } else {
        int ii = t - (NB + NA + NT);
        float ki = pim[ii];
        float g = -ki;
        unsigned cp[48]; float hold[12];
        #pragma unroll
        for (int j = 0; j < 8; ++j) {
            int s = sbase + j;
            out[(size_t)s * OUT_S + OFF_EI + ii] = ki * (1.0f - c2i[s * NI + ii]);
            const float4* dd = (const float4*)(dc2 + ((size_t)s * NI + ii) * 12);
            float4 dA = dd[0], dB = dd[1], dC = dd[2];
            float v[12] = {dA.x*g, dA.y*g, dA.z*g, dA.w*g, dB.x*g, dB.y*g,
                           dB.z*g, dB.w*g, dC.x*g, dC.y*g, dC.z*g, dC.w*g};
            if ((j & 1) == 0) {
                #pragma unroll
                for (int k = 0; k < 12; ++k) hold[k] = v[k];
            } else {
                int q = j >> 1;
                #pragma unroll
                for (int k = 0; k < 12; ++k)
                    cp[(k / 3) * 12 + (k % 3) * 4 + q] = pkrtz(hold[k], v[k]);
            }
        }
        #pragma unroll
        for (int sl = 0; sl < 4; ++sl) {
            uint4* dst = (uint4*)(cB + (size_t)posb[BF_IMP + ii * 4 + sl] * 24 + h * 12);
            #pragma unroll
            for (int k = 0; k < 3; ++k)
                dst[k] = make_uint4(cp[sl*12+4*k], cp[sl*12+4*k+1], cp[sl*12+4*k+2], cp[sl*12+4*k+3]);
        }
    }
}

// ---------------------------------------------------------------------------
// K6: gather — wave per atom; contiguous fp8 vdw list + f16 bonded list.
__global__ __launch_bounds__(256, 2) void gather2_kernel(
    const unsigned* __restrict__ cV, const unsigned* __restrict__ cB,
    const int* __restrict__ startxV, const int* __restrict__ startxB,
    float* __restrict__ out)
{
    __shared__ float red[4][48];
    int wv = threadIdx.x >> 6, lane = threadIdx.x & 63;
    int a0 = blockIdx.x * 4;
    int a = a0 + wv;

    float acc[48];
    #pragma unroll
    for (int k = 0; k < 48; ++k) acc[k] = 0.0f;

    {
        int base = startxV[a], endp = startxV[a + 1];
        for (int i = base + lane; i < endp; i += 64) {
            const uint4* e = (const uint4*)(cV + (size_t)i * 12);
            uint4 q0 = e[0], q1 = e[1], q2 = e[2];
            unsigned wd[12] = {q0.x, q0.y, q0.z, q0.w,
                               q1.x, q1.y, q1.z, q1.w,
                               q2.x, q2.y, q2.z, q2.w};
            #pragma unroll
            for (int wi = 0; wi < 12; ++wi) {
                int comp = wi >> 2, q = wi & 3;
                f2v lo = __builtin_amdgcn_cvt_pk_f32_fp8(wd[wi], false);
                f2v hi = __builtin_amdgcn_cvt_pk_f32_fp8(wd[wi], true);
                acc[comp * 16 + 4 * q + 0] += lo.x;
                acc[comp * 16 + 4 * q + 1] += lo.y;
                acc[comp * 16 + 4 * q + 2] += hi.x;
                acc[comp * 16 + 4 * q + 3] += hi.y;
            }
        }
    }
    {
        int base = startxB[a], endp = startxB[a + 1];
        for (int i = base + lane; i < endp; i += 64) {
            const uint4* e = (const uint4*)(cB + (size_t)i * 24);
            uint4 q0 = e[0], q1 = e[1], q2 = e[2], q3 = e[3], q4 = e[4], q5 = e[5];
            unsigned wd[24] = {q0.x, q0.y, q0.z, q0.w, q1.x, q1.y, q1.z, q1.w,
                               q2.x, q2.y, q2.z, q2.w, q3.x, q3.y, q3.z, q3.w,
                               q4.x, q4.y, q4.z, q4.w, q5.x, q5.y, q5.z, q5.w};
            #pragma unroll
            for (int wi = 0; wi < 24; ++wi) {
                int h = wi / 12, rem = wi - h * 12;
                int comp = rem >> 2, qq = rem & 3;
                int s0 = h * 8 + 2 * qq;
                __half2 hh = __builtin_bit_cast(__half2, wd[wi]);
                acc[comp * 16 + s0]     += __low2float(hh);
                acc[comp * 16 + s0 + 1] += __high2float(hh);
            }
        }
    }

    #pragma unroll
    for (int off = 32; off > 0; off >>= 1) {
        #pragma unroll
        for (int k = 0; k < 48; ++k)
            acc[k] += __shfl_down(acc[k], off);
    }
    if (lane == 0) {
        #pragma unroll
        for (int k = 0; k < 48; ++k) red[wv][k] = acc[k];
    }
    __syncthreads();
    int th = threadIdx.x;
    if (th < 192) {
        int s = th / 12, idx = th % 12;
        int ai = idx / 3, comp = idx % 3;
        out[(size_t)s * OUT_S + OFF_F + 3 * (a0 + ai) + comp] = red[ai][comp * 16 + s];
    }
}

// ---------------------------------------------------------------------------
extern "C" void kernel_launch(void* const* d_in, const int* in_sizes, int n_in,
                              void* d_out, int out_size, void* d_ws, size_t ws_size,
                              hipStream_t stream) {
    const float* lb  = (const float*)d_in[0];
    const float* th  = (const float*)d_in[1];
    const float* lv  = (const float*)d_in[2];
    const float* sc  = (const float*)d_in[3];
    const float* c2i = (const float*)d_in[4];
    const float* v14 = (const float*)d_in[5];
    const float* q14 = (const float*)d_in[6];
    const float* pb  = (const float*)d_in[7];
    const float* pa  = (const float*)d_in[8];
    const float* pv  = (const float*)d_in[9];
    const float* pc  = (const float*)d_in[10];
    const float* pt  = (const float*)d_in[11];
    const float* pim = (const float*)d_in[12];
    const float* dlb = (const float*)d_in[13];
    const float* dth = (const float*)d_in[14];
    const float* dlv = (const float*)d_in[15];
    const float* dtt = (const float*)d_in[16];
    const float* dc2 = (const float*)d_in[17];
    const int* nb    = (const int*)d_in[18];
    const int* bidx  = (const int*)d_in[19];
    const int* aidx  = (const int*)d_in[20];
    const int* nbi   = (const int*)d_in[21];
    const int* tidx  = (const int*)d_in[22];
    const int* iidx  = (const int*)d_in[23];
    float* out = (float*)d_out;

    unsigned* cV      = (unsigned*)d_ws;                    // NENTV*12 u32
    unsigned* cB      = cV + (size_t)NENTV * 12;            // NBF*24 u32
    float4*   wsp     = (float4*)(cB + (size_t)NBF * 24);   // NV
    int*      posv    = (int*)(wsp + NV);                   // 2*NV
    int*      posb    = posv + 2 * NV;                      // NBF
    int*      countsV = posb + NBF;                         // NCB*N_ATOMS
    int*      countsB = countsV + (size_t)NCB * N_ATOMS;    // NCB*N_ATOMS
    int*      totalV  = countsB + (size_t)NCB * N_ATOMS;    // N_ATOMS
    int*      totalB  = totalV + N_ATOMS;                   // N_ATOMS
    int*      startxV = totalB + N_ATOMS;                   // N_ATOMS+1
    int*      startxB = startxV + (N_ATOMS + 1);            // N_ATOMS+1

    inithist_kernel<<<NCB + VBLKS, 256, 0, stream>>>(
        v14, q14, pv, pc, nb, nbi, bidx, aidx, tidx, iidx,
        wsp, countsV, countsB, out);
    colscan2_kernel<<<(2 * N_ATOMS + 255) / 256, 256, 0, stream>>>(countsV, countsB, totalV, totalB);
    scan2_kernel<<<1, 64, 0, stream>>>(totalV, totalB, startxV, startxB);
    place2_kernel<<<NCB, 256, 0, stream>>>(nbi, bidx, aidx, tidx, iidx,
                                           countsV, countsB, startxV, startxB, posv, posb);
    work_kernel<<<BBH + VBLKS, 256, 0, stream>>>(
        lv, dlv, wsp, posv, lb, th, sc, c2i, pb, pa, pt, pim,
        dlb, dth, dtt, dc2, posb, cV, cB, out);
    gather2_kernel<<<N_ATOMS / 4, 256, 0, stream>>>(cV, cB, startxV, startxB, out);
}

// Round 18
// 133.265 us; speedup vs baseline: 1.4407x; 1.0061x over previous
//
#include <hip/hip_runtime.h>
#include <hip/hip_fp16.h>

#define NS 16
#define N_ATOMS 2000
#define NB 2000
#define NA 4000
#define NV 400000
#define NT 6000
#define NI 1000

#define OUT_S 819001
#define OFF_EB 0
#define OFF_EA 2000
#define OFF_EUB 6000
#define OFF_EV 6001
#define OFF_EC 406001
#define OFF_ET 806001
#define OFF_EI 812001
#define OFF_F 813001

#define CHARGE_TENTH 1.8222615f

#define NBF 44000
#define BF_BOND 0
#define BF_ANGLE 4000
#define BF_TORS 16000
#define BF_IMP 40000
#define NENTV (NV * 2)
#define NBOND_TOT (NB + NA + NT + NI)   // 13000
#define NITEMS (NV + NB + NA + NT + NI) // 413000
#define NCB 64
#define IPB ((NITEMS + NCB - 1) / NCB)  // 6454
#define VBLKS ((NV + 255) / 256)        // 1563
#define BBH ((NBOND_TOT * 2 + 255) / 256)   // 102

typedef float f2v __attribute__((ext_vector_type(2)));

__device__ __forceinline__ unsigned pkrtz(float a, float b) {
    typedef __fp16 hv2 __attribute__((ext_vector_type(2)));
    hv2 h = __builtin_amdgcn_cvt_pkrtz(a, b);
    return __builtin_bit_cast(unsigned, h);
}

// ---------------------------------------------------------------------------
// K1: fused — blocks [0,NCB): LDS histograms; blocks [NCB,..): params + E_ub.
__global__ __launch_bounds__(256, 4) void inithist_kernel(
    const float* __restrict__ v14, const float* __restrict__ q14,
    const float* __restrict__ pv, const float* __restrict__ pc,
    const int* __restrict__ nb,
    const int* __restrict__ nbi, const int* __restrict__ bidx,
    const int* __restrict__ aidx, const int* __restrict__ tidx,
    const int* __restrict__ iidx,
    float4* __restrict__ ws, int* __restrict__ countsV, int* __restrict__ countsB,
    float* __restrict__ out)
{
    __shared__ int hV[N_ATOMS];
    __shared__ int hB[N_ATOMS];
    int tid = threadIdx.x, b = blockIdx.x;

    if (b >= NCB) {
        int idx = (b - NCB) * 256 + tid;
        if (idx < NS) out[(size_t)idx * OUT_S + OFF_EUB] = 0.0f;
        if (idx < NV) {
            int v = idx;
            int i = nb[v];
            int j = nb[NV + v];
            float2 pvi = ((const float2*)pv)[i];
            float2 pvj = ((const float2*)pv)[j];
            float sigma = pvi.x + pvj.x;
            float sig2 = sigma * sigma;
            float4 w;
            w.x = sig2 * sig2 * sig2;
            w.y = pvi.y * pvj.y * 0.01f * v14[v];
            w.z = (CHARGE_TENTH * CHARGE_TENTH) * pc[i] * pc[j] * q14[v];
            w.w = 0.0f;
            ws[v] = w;
        }
        return;
    }

    for (int k = tid; k < N_ATOMS; k += 256) { hV[k] = 0; hB[k] = 0; }
    __syncthreads();
    int t0 = b * IPB, t1 = t0 + IPB; if (t1 > NITEMS) t1 = NITEMS;
    for (int t = t0 + tid; t < t1; t += 256) {
        if (t < NV) {
            atomicAdd(&hV[nbi[2 * t]], 1);
            atomicAdd(&hV[nbi[2 * t + 1]], 1);
        } else if (t < NV + NB) {
            int x = t - NV;
            atomicAdd(&hB[bidx[2 * x]], 1);
            atomicAdd(&hB[bidx[2 * x + 1]], 1);
        } else if (t < NV + NB + NA) {
            int x = t - (NV + NB);
            atomicAdd(&hB[aidx[3 * x]], 1);
            atomicAdd(&hB[aidx[3 * x + 1]], 1);
            atomicAdd(&hB[aidx[3 * x + 2]], 1);
        } else if (t < NV + NB + NA + NT) {
            int x = t - (NV + NB + NA);
            #pragma unroll
            for (int p = 0; p < 4; ++p) atomicAdd(&hB[tidx[4 * x + p]], 1);
        } else {
            int x = t - (NV + NB + NA + NT);
            #pragma unroll
            for (int p = 0; p < 4; ++p) atomicAdd(&hB[iidx[4 * x + p]], 1);
        }
    }
    __syncthreads();
    for (int k = tid; k < N_ATOMS; k += 256) {
        countsV[(size_t)b * N_ATOMS + k] = hV[k];
        countsB[(size_t)b * N_ATOMS + k] = hB[k];
    }
}

// K2: column scans.
__global__ __launch_bounds__(256) void colscan2_kernel(
    int* __restrict__ countsV, int* __restrict__ countsB,
    int* __restrict__ totalV, int* __restrict__ totalB)
{
    int a = blockIdx.x * 256 + threadIdx.x;
    if (a < N_ATOMS) {
        int pre = 0;
        for (int b = 0; b < NCB; ++b) {
            int c = countsV[(size_t)b * N_ATOMS + a];
            countsV[(size_t)b * N_ATOMS + a] = pre;
            pre += c;
        }
        totalV[a] = pre;
    } else if (a < 2 * N_ATOMS) {
        int aa = a - N_ATOMS;
        int pre = 0;
        for (int b = 0; b < NCB; ++b) {
            int c = countsB[(size_t)b * N_ATOMS + aa];
            countsB[(size_t)b * N_ATOMS + aa] = pre;
            pre += c;
        }
        totalB[aa] = pre;
    }
}

// K3: single-wave exclusive scans.
__device__ __forceinline__ void wave_scan(const int* __restrict__ total,
                                          int* __restrict__ startx, int lane)
{
    const int CH = (N_ATOMS + 63) / 64;
    int a0 = lane * CH, a1 = a0 + CH; if (a1 > N_ATOMS) a1 = N_ATOMS;
    int tot = 0;
    for (int a = a0; a < a1; ++a) tot += total[a];
    int incl = tot;
    #pragma unroll
    for (int off = 1; off < 64; off <<= 1) {
        int n = __shfl_up(incl, off);
        if (lane >= off) incl += n;
    }
    int run = incl - tot;
    for (int a = a0; a < a1; ++a) { startx[a] = run; run += total[a]; }
    if (lane == 63) startx[N_ATOMS] = run;
}

__global__ __launch_bounds__(64) void scan2_kernel(
    const int* __restrict__ totalV, const int* __restrict__ totalB,
    int* __restrict__ startxV, int* __restrict__ startxB)
{
    int lane = threadIdx.x;
    wave_scan(totalV, startxV, lane);
    wave_scan(totalB, startxB, lane);
}

// K4: placement — inverse permutations.
__global__ __launch_bounds__(256, 4) void place2_kernel(
    const int* __restrict__ nbi, const int* __restrict__ bidx,
    const int* __restrict__ aidx, const int* __restrict__ tidx,
    const int* __restrict__ iidx,
    const int* __restrict__ countsV, const int* __restrict__ countsB,
    const int* __restrict__ startxV, const int* __restrict__ startxB,
    int* __restrict__ posv, int* __restrict__ posb)
{
    __shared__ int curV[N_ATOMS];
    __shared__ int curB[N_ATOMS];
    int tid = threadIdx.x, b = blockIdx.x;
    for (int k = tid; k < N_ATOMS; k += 256) {
        curV[k] = startxV[k] + countsV[(size_t)b * N_ATOMS + k];
        curB[k] = startxB[k] + countsB[(size_t)b * N_ATOMS + k];
    }
    __syncthreads();
    int t0 = b * IPB, t1 = t0 + IPB; if (t1 > NITEMS) t1 = NITEMS;
    for (int t = t0 + tid; t < t1; t += 256) {
        if (t < NV) {
            posv[2 * t]     = atomicAdd(&curV[nbi[2 * t]], 1);
            posv[2 * t + 1] = atomicAdd(&curV[nbi[2 * t + 1]], 1);
        } else if (t < NV + NB) {
            int x = t - NV;
            #pragma unroll
            for (int sl = 0; sl < 2; ++sl)
                posb[BF_BOND + x * 2 + sl] = atomicAdd(&curB[bidx[2 * x + sl]], 1);
        } else if (t < NV + NB + NA) {
            int x = t - (NV + NB);
            #pragma unroll
            for (int sl = 0; sl < 3; ++sl)
                posb[BF_ANGLE + x * 3 + sl] = atomicAdd(&curB[aidx[3 * x + sl]], 1);
        } else if (t < NV + NB + NA + NT) {
            int x = t - (NV + NB + NA);
            #pragma unroll
            for (int sl = 0; sl < 4; ++sl)
                posb[BF_TORS + x * 4 + sl] = atomicAdd(&curB[tidx[4 * x + sl]], 1);
        } else {
            int x = t - (NV + NB + NA + NT);
            #pragma unroll
            for (int sl = 0; sl < 4; ++sl)
                posb[BF_IMP + x * 4 + sl] = atomicAdd(&curB[iidx[4 * x + sl]], 1);
        }
    }
}

// ---------------------------------------------------------------------------
// K5: fused work. Blocks [0,BBH): bonded h-split; blocks [BBH,..): phaseA
// per-v with WAVE-COOPERATIVE COALESCED dlv loads staged through per-wave
// LDS (double-buffered, 1-iteration prefetch, no asm barriers): every
// in-flight cache line is fully consumed (MSHR useful-bytes x3).
__global__ __launch_bounds__(256, 4) void work_kernel(
    const float* __restrict__ lv, const float* __restrict__ dlv,
    const float4* __restrict__ ws, const int* __restrict__ posv,
    const float* __restrict__ lb, const float* __restrict__ th,
    const float* __restrict__ sc, const float* __restrict__ c2i,
    const float* __restrict__ pb, const float* __restrict__ pa,
    const float* __restrict__ pt, const float* __restrict__ pim,
    const float* __restrict__ dlb, const float* __restrict__ dth,
    const float* __restrict__ dtt, const float* __restrict__ dc2,
    const int* __restrict__ posb,
    unsigned* __restrict__ cV, unsigned* __restrict__ cB,
    float* __restrict__ out)
{
    __shared__ float4 stg[4][2][96];   // per-wave double-buffered dlv tile
    int x = blockIdx.x;
    int tid = threadIdx.x;

    if (x >= BBH) {
        // ---------------- phaseA ----------------
        int wv = tid >> 6, lane = tid & 63;
        int vbase = (x - BBH) * 256 + wv * 64;
        if (vbase >= NV) return;          // NV % 64 == 0: waves fully in/out
        int v = vbase + lane;
        float4 w = ws[v];
        int2 pp = *(const int2*)(posv + 2 * v);
        const float4* dfl4 = (const float4*)dlv;

        unsigned cp[24];
        float hold[3][6];
        float ev[16], ec[16];

        // prologue: issue s=0 loads
        size_t fb = (size_t)vbase * 6 / 4;
        float4 t0 = dfl4[fb + lane];
        float4 t1;
        if (lane < 32) t1 = dfl4[fb + 64 + lane];
        float rr = lv[v];

        #pragma unroll
        for (int s = 0; s < 16; ++s) {
            float4* st = stg[wv][s & 1];
            st[lane] = t0;
            if (lane < 32) st[64 + lane] = t1;
            float r = rr;
            if (s + 1 < 16) {
                size_t fbn = ((size_t)(s + 1) * NV + vbase) * 6 / 4;
                t0 = dfl4[fbn + lane];
                if (lane < 32) t1 = dfl4[fbn + 64 + lane];
                rr = lv[(size_t)(s + 1) * NV + v];
            }
            const float2* stp = (const float2*)st;
            float2 dA = stp[3 * lane];
            float2 dB = stp[3 * lane + 1];
            float2 dC = stp[3 * lane + 2];

            float rinv = __builtin_amdgcn_rcpf(r);
            float r2inv = rinv * rinv;
            float r6inv = r2inv * r2inv * r2inv;
            float t = w.x * r6inv;
            ev[s] = w.y * (t * t - 2.0f * t);
            ec[s] = w.z * rinv;
            float fsv = 12.0f * w.y * t * (1.0f - t) * rinv - w.z * r2inv;
            float cc[6];
            cc[0] = dA.x * fsv; cc[1] = dA.y * fsv; cc[2] = dB.x * fsv;
            cc[3] = dB.y * fsv; cc[4] = dC.x * fsv; cc[5] = dC.y * fsv;
            int m = s & 3;
            if (m < 3) {
                #pragma unroll
                for (int k = 0; k < 6; ++k) hold[m][k] = cc[k];
            } else {
                int q = s >> 2;
                #pragma unroll
                for (int k = 0; k < 6; ++k) {
                    int t0i = __builtin_amdgcn_cvt_pk_fp8_f32(hold[0][k], hold[1][k], 0, false);
                    t0i = __builtin_amdgcn_cvt_pk_fp8_f32(hold[2][k], cc[k], t0i, true);
                    cp[(k / 3) * 12 + (k % 3) * 4 + q] = (unsigned)t0i;
                }
            }
        }
        uint4* dst0 = (uint4*)(cV + (size_t)pp.x * 12);
        #pragma unroll
        for (int k = 0; k < 3; ++k)
            dst0[k] = make_uint4(cp[4 * k], cp[4 * k + 1], cp[4 * k + 2], cp[4 * k + 3]);
        uint4* dst1 = (uint4*)(cV + (size_t)pp.y * 12);
        #pragma unroll
        for (int k = 0; k < 3; ++k)
            dst1[k] = make_uint4(cp[12 + 4 * k], cp[12 + 4 * k + 1], cp[12 + 4 * k + 2], cp[12 + 4 * k + 3]);
        #pragma unroll
        for (int s = 0; s < 16; ++s) {
            out[(size_t)s * OUT_S + OFF_EV + v] = ev[s];
            out[(size_t)s * OUT_S + OFF_EC + v] = ec[s];
        }
        return;
    }

    // ---------------- bonded, h-split ----------------
    int idx = x * 256 + tid;
    int h = idx & 1;           // sample-half
    int t = idx >> 1;          // term id
    if (t >= NBOND_TOT) return;
    int sbase = h * 8;

    if (t < NB) {
        int b = t;
        float2 p = ((const float2*)pb)[b];
        float K = p.x * 100.0f;
        unsigned cp[24]; float hold[6];
        #pragma unroll
        for (int j = 0; j < 8; ++j) {
            int s = sbase + j;
            float d = lb[s * NB + b] - p.y;
            out[(size_t)s * OUT_S + OFF_EB + b] = K * d * d;
            float g = 2.0f * K * d;
            const float2* dd = (const float2*)(dlb + ((size_t)s * NB + b) * 6);
            float2 dA = dd[0], dB = dd[1], dC = dd[2];
            float v0 = dA.x * g, v1 = dA.y * g, v2 = dB.x * g;
            float v3 = dB.y * g, v4 = dC.x * g, v5 = dC.y * g;
            if ((j & 1) == 0) { hold[0]=v0; hold[1]=v1; hold[2]=v2; hold[3]=v3; hold[4]=v4; hold[5]=v5; }
            else {
                int q = j >> 1;
                cp[0*12 + 0*4 + q] = pkrtz(hold[0], v0);
                cp[0*12 + 1*4 + q] = pkrtz(hold[1], v1);
                cp[0*12 + 2*4 + q] = pkrtz(hold[2], v2);
                cp[1*12 + 0*4 + q] = pkrtz(hold[3], v3);
                cp[1*12 + 1*4 + q] = pkrtz(hold[4], v4);
                cp[1*12 + 2*4 + q] = pkrtz(hold[5], v5);
            }
        }
        #pragma unroll
        for (int sl = 0; sl < 2; ++sl) {
            uint4* dst = (uint4*)(cB + (size_t)posb[BF_BOND + b * 2 + sl] * 24 + h * 12);
            #pragma unroll
            for (int k = 0; k < 3; ++k)
                dst[k] = make_uint4(cp[sl*12+4*k], cp[sl*12+4*k+1], cp[sl*12+4*k+2], cp[sl*12+4*k+3]);
        }
    } else if (t < NB + NA) {
        int a = t - NB;
        float2 p = ((const float2*)pa)[a];
        float Ka = p.x * 10.0f;
        float th0 = p.y * 0.31415926535f;
        unsigned cp[36]; float hold[9];
        #pragma unroll
        for (int j = 0; j < 8; ++j) {
            int s = sbase + j;
            float da = th[s * NA + a] - th0;
            out[(size_t)s * OUT_S + OFF_EA + a] = Ka * da * da;
            float g = 2.0f * Ka * da;
            const float* dd = dth + ((size_t)s * NA + a) * 9;
            float v[9];
            #pragma unroll
            for (int k = 0; k < 9; ++k) v[k] = dd[k] * g;
            if ((j & 1) == 0) {
                #pragma unroll
                for (int k = 0; k < 9; ++k) hold[k] = v[k];
            } else {
                int q = j >> 1;
                #pragma unroll
                for (int k = 0; k < 9; ++k)
                    cp[(k / 3) * 12 + (k % 3) * 4 + q] = pkrtz(hold[k], v[k]);
            }
        }
        #pragma unroll
        for (int sl = 0; sl < 3; ++sl) {
            uint4* dst = (uint4*)(cB + (size_t)posb[BF_ANGLE + a * 3 + sl] * 24 + h * 12);
            #pragma unroll
            for (int k = 0; k < 3; ++k)
                dst[k] = make_uint4(cp[sl*12+4*k], cp[sl*12+4*k+1], cp[sl*12+4*k+2], cp[sl*12+4*k+3]);
        }
    } else if (t < NB + NA + NT) {
        int tt = t - (NB + NA);
        float4 p4 = ((const float4*)pt)[tt];
        unsigned cp[48]; float hold[12];
        #pragma unroll
        for (int j = 0; j < 8; ++j) {
            int s = sbase + j;
            const float4* s8 = (const float4*)(sc + ((size_t)s * NT + tt) * 8);
            float4 sA = s8[0], sB = s8[1];
            out[(size_t)s * OUT_S + OFF_ET + tt] =
                sA.y * p4.x + sA.w * p4.y + sB.y * p4.z + sB.w * p4.w;
            float g = -(sA.x * p4.x + sA.z * p4.y * 2.0f + sB.x * p4.z * 3.0f + sB.z * p4.w * 4.0f);
            const float4* dd = (const float4*)(dtt + ((size_t)s * NT + tt) * 12);
            float4 dA = dd[0], dB = dd[1], dC = dd[2];
            float v[12] = {dA.x*g, dA.y*g, dA.z*g, dA.w*g, dB.x*g, dB.y*g,
                           dB.z*g, dB.w*g, dC.x*g, dC.y*g, dC.z*g, dC.w*g};
            if ((j & 1) == 0) {
                #pragma unroll
                for (int k = 0; k < 12; ++k) hold[k] = v[k];
            } else {
                int q = j >> 1;
                #pragma unroll
                for (int k = 0; k < 12; ++k)
                    cp[(k / 3) * 12 + (k % 3) * 4 + q] = pkrtz(hold[k], v[k]);
            }
        }
        #pragma unroll
        for (int sl = 0; sl < 4; ++sl) {
            uint4* dst = (uint4*)(cB + (size_t)posb[BF_TORS + tt * 4 + sl] * 24 + h * 12);
            #pragma unroll
            for (int k = 0; k < 3; ++k)
                dst[k] = make_uint4(cp[sl*12+4*k], cp[sl*12+4*k+1], cp[sl*12+4*k+2], cp[sl*12+4*k+3]);
        }
    } else {
        int ii = t - (NB + NA + NT);
        float ki = pim[ii];
        float g = -ki;
        unsigned cp[48]; float hold[12];
        #pragma unroll
        for (int j = 0; j < 8; ++j) {
            int s = sbase + j;
            out[(size_t)s * OUT_S + OFF_EI + ii] = ki * (1.0f - c2i[s * NI + ii]);
            const float4* dd = (const float4*)(dc2 + ((size_t)s * NI + ii) * 12);
            float4 dA = dd[0], dB = dd[1], dC = dd[2];
            float v[12] = {dA.x*g, dA.y*g, dA.z*g, dA.w*g, dB.x*g, dB.y*g,
                           dB.z*g, dB.w*g, dC.x*g, dC.y*g, dC.z*g, dC.w*g};
            if ((j & 1) == 0) {
                #pragma unroll
                for (int k = 0; k < 12; ++k) hold[k] = v[k];
            } else {
                int q = j >> 1;
                #pragma unroll
                for (int k = 0; k < 12; ++k)
                    cp[(k / 3) * 12 + (k % 3) * 4 + q] = pkrtz(hold[k], v[k]);
            }
        }
        #pragma unroll
        for (int sl = 0; sl < 4; ++sl) {
            uint4* dst = (uint4*)(cB + (size_t)posb[BF_IMP + ii * 4 + sl] * 24 + h * 12);
            #pragma unroll
            for (int k = 0; k < 3; ++k)
                dst[k] = make_uint4(cp[sl*12+4*k], cp[sl*12+4*k+1], cp[sl*12+4*k+2], cp[sl*12+4*k+3]);
        }
    }
}

// ---------------------------------------------------------------------------
// K6: gather — wave per atom; contiguous fp8 vdw list + f16 bonded list.
__global__ __launch_bounds__(256, 2) void gather2_kernel(
    const unsigned* __restrict__ cV, const unsigned* __restrict__ cB,
    const int* __restrict__ startxV, const int* __restrict__ startxB,
    float* __restrict__ out)
{
    __shared__ float red[4][48];
    int wv = threadIdx.x >> 6, lane = threadIdx.x & 63;
    int a0 = blockIdx.x * 4;
    int a = a0 + wv;

    float acc[48];
    #pragma unroll
    for (int k = 0; k < 48; ++k) acc[k] = 0.0f;

    {
        int base = startxV[a], endp = startxV[a + 1];
        for (int i = base + lane; i < endp; i += 64) {
            const uint4* e = (const uint4*)(cV + (size_t)i * 12);
            uint4 q0 = e[0], q1 = e[1], q2 = e[2];
            unsigned wd[12] = {q0.x, q0.y, q0.z, q0.w,
                               q1.x, q1.y, q1.z, q1.w,
                               q2.x, q2.y, q2.z, q2.w};
            #pragma unroll
            for (int wi = 0; wi < 12; ++wi) {
                int comp = wi >> 2, q = wi & 3;
                f2v lo = __builtin_amdgcn_cvt_pk_f32_fp8(wd[wi], false);
                f2v hi = __builtin_amdgcn_cvt_pk_f32_fp8(wd[wi], true);
                acc[comp * 16 + 4 * q + 0] += lo.x;
                acc[comp * 16 + 4 * q + 1] += lo.y;
                acc[comp * 16 + 4 * q + 2] += hi.x;
                acc[comp * 16 + 4 * q + 3] += hi.y;
            }
        }
    }
    {
        int base = startxB[a], endp = startxB[a + 1];
        for (int i = base + lane; i < endp; i += 64) {
            const uint4* e = (const uint4*)(cB + (size_t)i * 24);
            uint4 q0 = e[0], q1 = e[1], q2 = e[2], q3 = e[3], q4 = e[4], q5 = e[5];
            unsigned wd[24] = {q0.x, q0.y, q0.z, q0.w, q1.x, q1.y, q1.z, q1.w,
                               q2.x, q2.y, q2.z, q2.w, q3.x, q3.y, q3.z, q3.w,
                               q4.x, q4.y, q4.z, q4.w, q5.x, q5.y, q5.z, q5.w};
            #pragma unroll
            for (int wi = 0; wi < 24; ++wi) {
                int h = wi / 12, rem = wi - h * 12;
                int comp = rem >> 2, qq = rem & 3;
                int s0 = h * 8 + 2 * qq;
                __half2 hh = __builtin_bit_cast(__half2, wd[wi]);
                acc[comp * 16 + s0]     += __low2float(hh);
                acc[comp * 16 + s0 + 1] += __high2float(hh);
            }
        }
    }

    #pragma unroll
    for (int off = 32; off > 0; off >>= 1) {
        #pragma unroll
        for (int k = 0; k < 48; ++k)
            acc[k] += __shfl_down(acc[k], off);
    }
    if (lane == 0) {
        #pragma unroll
        for (int k = 0; k < 48; ++k) red[wv][k] = acc[k];
    }
    __syncthreads();
    int th = threadIdx.x;
    if (th < 192) {
        int s = th / 12, idx = th % 12;
        int ai = idx / 3, comp = idx % 3;
        out[(size_t)s * OUT_S + OFF_F + 3 * (a0 + ai) + comp] = red[ai][comp * 16 + s];
    }
}

// ---------------------------------------------------------------------------
extern "C" void kernel_launch(void* const* d_in, const int* in_sizes, int n_in,
                              void* d_out, int out_size, void* d_ws, size_t ws_size,
                              hipStream_t stream) {
    const float* lb  = (const float*)d_in[0];
    const float* th  = (const float*)d_in[1];
    const float* lv  = (const float*)d_in[2];
    const float* sc  = (const float*)d_in[3];
    const float* c2i = (const float*)d_in[4];
    const float* v14 = (const float*)d_in[5];
    const float* q14 = (const float*)d_in[6];
    const float* pb  = (const float*)d_in[7];
    const float* pa  = (const float*)d_in[8];
    const float* pv  = (const float*)d_in[9];
    const float* pc  = (const float*)d_in[10];
    const float* pt  = (const float*)d_in[11];
    const float* pim = (const float*)d_in[12];
    const float* dlb = (const float*)d_in[13];
    const float* dth = (const float*)d_in[14];
    const float* dlv = (const float*)d_in[15];
    const float* dtt = (const float*)d_in[16];
    const float* dc2 = (const float*)d_in[17];
    const int* nb    = (const int*)d_in[18];
    const int* bidx  = (const int*)d_in[19];
    const int* aidx  = (const int*)d_in[20];
    const int* nbi   = (const int*)d_in[21];
    const int* tidx  = (const int*)d_in[22];
    const int* iidx  = (const int*)d_in[23];
    float* out = (float*)d_out;

    unsigned* cV      = (unsigned*)d_ws;                    // NENTV*12 u32
    unsigned* cB      = cV + (size_t)NENTV * 12;            // NBF*24 u32
    float4*   wsp     = (float4*)(cB + (size_t)NBF * 24);   // NV
    int*      posv    = (int*)(wsp + NV);                   // 2*NV
    int*      posb    = posv + 2 * NV;                      // NBF
    int*      countsV = posb + NBF;                         // NCB*N_ATOMS
    int*      countsB = countsV + (size_t)NCB * N_ATOMS;    // NCB*N_ATOMS
    int*      totalV  = countsB + (size_t)NCB * N_ATOMS;    // N_ATOMS
    int*      totalB  = totalV + N_ATOMS;                   // N_ATOMS
    int*      startxV = totalB + N_ATOMS;                   // N_ATOMS+1
    int*      startxB = startxV + (N_ATOMS + 1);            // N_ATOMS+1

    inithist_kernel<<<NCB + VBLKS, 256, 0, stream>>>(
        v14, q14, pv, pc, nb, nbi, bidx, aidx, tidx, iidx,
        wsp, countsV, countsB, out);
    colscan2_kernel<<<(2 * N_ATOMS + 255) / 256, 256, 0, stream>>>(countsV, countsB, totalV, totalB);
    scan2_kernel<<<1, 64, 0, stream>>>(totalV, totalB, startxV, startxB);
    place2_kernel<<<NCB, 256, 0, stream>>>(nbi, bidx, aidx, tidx, iidx,
                                           countsV, countsB, startxV, startxB, posv, posb);
    work_kernel<<<BBH + VBLKS, 256, 0, stream>>>(
        lv, dlv, wsp, posv, lb, th, sc, c2i, pb, pa, pt, pim,
        dlb, dth, dtt, dc2, posb, cV, cB, out);
    gather2_kernel<<<N_ATOMS / 4, 256, 0, stream>>>(cV, cB, startxV, startxB, out);
}